// Round 11
// baseline (447.732 us; speedup 1.0000x reference)
//
#include <hip/hip_runtime.h>

#define B_ 4
#define CK 64
#define CV 512
#define HW_ 900
#define THW 7200
#define MT 96
#define QB 64
#define CVB 64           // cv per block (8 chunks)
#define NS 3             // m-splits
#define MSPL (THW / NS)  // 2400
#define NIT (MSPL / MT)  // 25
#define ETP 104          // e_t row stride in shorts (208B; ~2-way banks on b128 reads)

typedef __attribute__((ext_vector_type(4))) float f32x4;
typedef __attribute__((ext_vector_type(4))) float float4_;
typedef __attribute__((ext_vector_type(8))) short s16x8;
typedef __attribute__((ext_vector_type(4))) short s16x4;

__device__ __forceinline__ short f2bf(float f) {
  union { float f; unsigned u; } x; x.f = f;
  unsigned u = x.u;
  return (short)((u + 0x7fffu + ((u >> 16) & 1u)) >> 16);  // RNE to bf16
}

// Fused prep: [A] mk->mkT bf16 + asq  [B] qk->bf16*0.25*log2e  [C] mv->bf16  [D] qv->out
#define NBLK_A 113
#define NBLK_B 900
#define NBLK_C 14400
#define NBLK_D 1800
__global__ __launch_bounds__(256) void prep_kernel(const float* __restrict__ mk,
                                                   const float* __restrict__ qk,
                                                   const float* __restrict__ mv,
                                                   const float* __restrict__ qv,
                                                   short* __restrict__ mkT,
                                                   short* __restrict__ qkb,
                                                   short* __restrict__ mvb,
                                                   float* __restrict__ asq,
                                                   float* __restrict__ out) {
  int bid = blockIdx.x;
  if (bid < NBLK_A) {  // mk transpose + |a|^2
    int idx = bid * 256 + threadIdx.x;
    if (idx >= B_ * THW) return;
    int b = idx / THW, m = idx - b * THW;
    const float* src = mk + (size_t)b * CK * THW + m;
    short row[CK];
    float acc = 0.f;
#pragma unroll
    for (int k = 0; k < CK; ++k) {
      float v = src[(size_t)k * THW];
      acc += v * v;
      row[k] = f2bf(v);
    }
    short* dst = mkT + (size_t)idx * CK;
#pragma unroll
    for (int c = 0; c < CK / 8; ++c)
      *reinterpret_cast<s16x8*>(dst + c * 8) = *reinterpret_cast<s16x8*>(row + c * 8);
    asq[idx] = acc * 0.18033688011112042f;  // 0.125 * log2(e)
  } else if (bid < NBLK_A + NBLK_B) {  // qk cast (exp2-units scale folded)
    int i = (bid - NBLK_A) * 256 + threadIdx.x;
    if (i < B_ * CK * HW_) qkb[i] = f2bf(qk[i] * 0.36067376022224085f);
  } else if (bid < NBLK_A + NBLK_B + NBLK_C) {  // mv cast
    int i = (bid - (NBLK_A + NBLK_B)) * 256 + threadIdx.x;
    float4_ v = reinterpret_cast<const float4_*>(mv)[i];
    s16x4 o;
    o[0] = f2bf(v[0]); o[1] = f2bf(v[1]); o[2] = f2bf(v[2]); o[3] = f2bf(v[3]);
    *reinterpret_cast<s16x4*>(mvb + (size_t)i * 4) = o;
  } else {  // qv passthrough -> out channels [CV, 2CV)
    int i = (bid - (NBLK_A + NBLK_B + NBLK_C)) * 256 + threadIdx.x;
    const int perb = CV * HW_ / 4;
    int b = i / perb, r = i - b * perb;
    float4_ v = reinterpret_cast<const float4_*>(qv)[i];
    *reinterpret_cast<float4_*>(out + (size_t)b * 2 * CV * HW_ + CV * HW_ + (size_t)r * 4) = v;
  }
}

// cv-split attention, register-prefetched mv (T14), LDS holds only E.
// Wave w owns cv [w*16, w*16+16) x all 64 q; logits for q-slice w computed once/block.
// grid (15 qb, 8 cvc * NS s, B). Writes unnormalized partial numerator + denom.
__global__ __launch_bounds__(256, 5) void attn_kernel(const short* __restrict__ mkT,
                                                      const short* __restrict__ qkb,
                                                      const short* __restrict__ mvb,
                                                      const float* __restrict__ asq,
                                                      float* __restrict__ part,
                                                      float* __restrict__ denomp) {
  __shared__ short e_t[64][ETP];  // 13,312 B — the only LDS

  const int tid = threadIdx.x;
  const int wave = tid >> 6, lane = tid & 63;
  const int g = lane >> 4, c = lane & 15;
  const int qb = blockIdx.x;
  const int cvc = blockIdx.y & 7, s = blockIdx.y >> 3;
  const int b = blockIdx.z;
  const int q = qb * QB + wave * 16 + c;  // this lane's logits q

  // hoist qk B-frags: lane holds B[k = ks*32 + g*8 + j][n = q]
  s16x8 qkf[2];
  {
    const short* qs = qkb + (size_t)b * CK * HW_;
#pragma unroll
    for (int ks = 0; ks < 2; ++ks)
#pragma unroll
      for (int j = 0; j < 8; ++j)
        qkf[ks][j] = (q < HW_) ? qs[(size_t)(ks * 32 + g * 8 + j) * HW_ + q] : (short)0;
  }

  f32x4 acc[4];  // [qf over q], wave's 16 cv rows
#pragma unroll
  for (int j = 0; j < 4; ++j) acc[j] = (f32x4){0.f, 0.f, 0.f, 0.f};
  float denom = 0.f;

  const short* mkb = mkT + (size_t)b * THW * CK;
  const short* mvB = mvb + ((size_t)b * CV + cvc * CVB + wave * 16) * THW;  // wave's cv rows
  const float* asb = asq + (size_t)b * THW;

  // prologue: load iter-0 mv A-frags into current register set
  s16x8 mvc[3], mvn[3];
  {
    const int m0 = s * MSPL;
#pragma unroll
    for (int ks = 0; ks < 3; ++ks)
      mvc[ks] = *reinterpret_cast<const s16x8*>(mvB + (size_t)c * THW + m0 + ks * 32 + g * 8);
  }

  for (int it = 0; it < NIT; ++it) {
    const int m0 = s * MSPL + it * MT;
    const int m1 = s * MSPL + (it + 1 < NIT ? it + 1 : it) * MT;

    // T14 issue-early: next iter's mv frags (consumed AFTER the next barrier pair)
#pragma unroll
    for (int ks = 0; ks < 3; ++ks)
      mvn[ks] = *reinterpret_cast<const s16x8*>(mvB + (size_t)c * THW + m1 + ks * 32 + g * 8);

    // logits: S = mk(96m x 64k) x qk(64k x 16q); E = exp2(S - asq) -> e_t (shared)
#pragma unroll
    for (int mf = 0; mf < 6; ++mf) {
      f32x4 sa = (f32x4){0.f, 0.f, 0.f, 0.f};
#pragma unroll
      for (int ks = 0; ks < 2; ++ks) {
        s16x8 a = *reinterpret_cast<const s16x8*>(
            mkb + (size_t)(m0 + mf * 16 + c) * CK + ks * 32 + g * 8);
        sa = __builtin_amdgcn_mfma_f32_16x16x32_bf16(a, qkf[ks], sa, 0, 0, 0);
      }
      f32x4 av = *reinterpret_cast<const f32x4*>(asb + m0 + mf * 16 + g * 4);
      s16x4 e4;
#pragma unroll
      for (int r = 0; r < 4; ++r) {
        float e = exp2f(sa[r] - av[r]);
        denom += e;
        union { float f; unsigned u; } cu; cu.f = e;
        e4[r] = (short)(cu.u >> 16);  // truncate to bf16
      }
      *reinterpret_cast<s16x4*>(&e_t[wave * 16 + c][mf * 16 + g * 4]) = e4;
    }
    __syncthreads();  // cross-wave: e_t complete

    // readout: acc(16cv x 64q) += mv(16cv x 96m)[regs] x E(96m x 64q)[LDS]
#pragma unroll
    for (int ks = 0; ks < 3; ++ks) {
      s16x8 ef[4];
#pragma unroll
      for (int qf = 0; qf < 4; ++qf)
        ef[qf] = *reinterpret_cast<const s16x8*>(&e_t[qf * 16 + c][ks * 32 + g * 8]);
#pragma unroll
      for (int qf = 0; qf < 4; ++qf)
        acc[qf] = __builtin_amdgcn_mfma_f32_16x16x32_bf16(mvc[ks], ef[qf], acc[qf], 0, 0, 0);
    }
    __syncthreads();  // WAR: next iter's e_t writes vs this iter's reads

    // rotate prefetch buffers (register copies; compiler renames)
#pragma unroll
    for (int ks = 0; ks < 3; ++ks) mvc[ks] = mvn[ks];
  }

  // denom: combine the 4 lane-groups (same q, disjoint m)
  denom += __shfl_xor(denom, 16);
  denom += __shfl_xor(denom, 32);
  if (cvc == 0 && lane < 16)
    denomp[((size_t)s * B_ + b) * 960 + qb * QB + wave * 16 + lane] = denom;

  // partial numerator: [block][cv_local 64][q_local 64]
  float* pb = part + (size_t)(((s * B_ + b) * 8 + cvc) * 15 + qb) * 4096;
#pragma unroll
  for (int qf = 0; qf < 4; ++qf)
#pragma unroll
    for (int r = 0; r < 4; ++r)
      pb[(size_t)(wave * 16 + g * 4 + r) * 64 + qf * 16 + c] = acc[qf][r];
}

// Sum NS partials, normalize, write mem half of out.
__global__ __launch_bounds__(256) void finalize_kernel(const float* __restrict__ part,
                                                       const float* __restrict__ denomp,
                                                       float* __restrict__ out) {
  int t = blockIdx.x * 256 + threadIdx.x;  // 491,520 threads
  int q4 = t & 15;
  int cvl = (t >> 4) & 63;
  int r1 = t >> 10;
  int qb = r1 % 15;
  int r2 = r1 / 15;
  int cvc = r2 & 7;
  int b = r2 >> 3;
  int q0 = qb * QB + q4 * 4;
  if (q0 >= HW_) return;
  const size_t sstr = (size_t)B_ * 8 * 15 * 4096;
  size_t base = (size_t)((b * 8 + cvc) * 15 + qb) * 4096 + cvl * 64 + q4 * 4;
  f32x4 p = *reinterpret_cast<const f32x4*>(part + base);
  f32x4 p1 = *reinterpret_cast<const f32x4*>(part + base + sstr);
  f32x4 p2 = *reinterpret_cast<const f32x4*>(part + base + 2 * sstr);
  p = p + p1 + p2;
  const float* dp = denomp + (size_t)b * 960 + q0;
  f32x4 d = *reinterpret_cast<const f32x4*>(dp) +
            *reinterpret_cast<const f32x4*>(dp + B_ * 960) +
            *reinterpret_cast<const f32x4*>(dp + 2 * B_ * 960);
  f32x4 o;
#pragma unroll
  for (int j = 0; j < 4; ++j) o[j] = p[j] / d[j];
  *reinterpret_cast<f32x4*>(out + (size_t)b * 2 * CV * HW_ +
                            (size_t)(cvc * CVB + cvl) * HW_ + q0) = o;
}

extern "C" void kernel_launch(void* const* d_in, const int* in_sizes, int n_in,
                              void* d_out, int out_size, void* d_ws, size_t ws_size,
                              hipStream_t stream) {
  const float* mk = (const float*)d_in[0];
  const float* qk = (const float*)d_in[1];
  const float* mv = (const float*)d_in[2];
  const float* qv = (const float*)d_in[3];
  float* out = (float*)d_out;

  // workspace layout (57,392,640 B total)
  char* ws = (char*)d_ws;
  short* mvb   = (short*)ws;                   // 29,491,200
  short* mkT   = (short*)(ws + 29491200);      //  3,686,400
  short* qkb   = (short*)(ws + 33177600);      //    460,800
  float* asq   = (float*)(ws + 33638400);      //    115,200
  float* denomp= (float*)(ws + 33753600);      //     46,080 (NS*B*960 f32)
  float* part  = (float*)(ws + 33799680);      // 23,592,960 (1440 blocks * 64*64 f32)

  prep_kernel<<<dim3(NBLK_A + NBLK_B + NBLK_C + NBLK_D), dim3(256), 0, stream>>>(
      mk, qk, mv, qv, mkT, qkb, mvb, asq, out);
  attn_kernel<<<dim3(15, 8 * NS, B_), dim3(256), 0, stream>>>(mkT, qkb, mvb, asq, part, denomp);
  finalize_kernel<<<dim3(1920), dim3(256), 0, stream>>>(part, denomp, out);
}